// Round 2
// baseline (203.950 us; speedup 1.0000x reference)
//
#include <hip/hip_runtime.h>
#include <hip/hip_bf16.h>

#define FDIM 256
#define K2   512
#define DNB  32
#define TM   32

typedef __attribute__((ext_vector_type(8))) short bf16x8;
typedef __attribute__((ext_vector_type(4))) float f32x4;

// Precomputed combined weights (recomputed every launch — deterministic).
__device__ __align__(16) unsigned short g_Wc[FDIM * K2]; // [o][k] bf16: k<256 -> W2a ; k>=256 -> C1
__device__ float g_c2[FDIM];
__device__ float g_c3[FDIM];
__device__ float g_W1s[FDIM];

__device__ __forceinline__ unsigned short f2bf(float f) {
    __hip_bfloat16 h = __float2bfloat16(f);
    return *reinterpret_cast<unsigned short*>(&h);
}

// ---------- W1s[j] = sum_k W1[j, 256+k] ----------
__global__ __launch_bounds__(64) void pre_w1s(const float* __restrict__ W1) {
    int j = blockIdx.x;
    int lane = threadIdx.x;
    const float4* row = (const float4*)(W1 + (size_t)j * K2 + FDIM);
    float4 v = row[lane];
    float s = v.x + v.y + v.z + v.w;
    #pragma unroll
    for (int d = 32; d; d >>= 1) s += __shfl_down(s, d);
    if (lane == 0) g_W1s[j] = s;
}

// ---------- c2[o], c3[o] ----------
__global__ __launch_bounds__(256) void pre_c23(const float* __restrict__ W2,
                                               const float* __restrict__ b1,
                                               const float* __restrict__ b2,
                                               float Dmul) {
    int o = blockIdx.x, j = threadIdx.x;
    float w2bj = W2[(size_t)o * K2 + FDIM + j];
    float t1 = g_W1s[j] * w2bj;
    float t2 = b1[j] * w2bj;
    #pragma unroll
    for (int d = 32; d; d >>= 1) { t1 += __shfl_down(t1, d); t2 += __shfl_down(t2, d); }
    __shared__ float r1[4], r2[4];
    int wv = j >> 6;
    if ((j & 63) == 0) { r1[wv] = t1; r2[wv] = t2; }
    __syncthreads();
    if (j == 0) {
        g_c2[o] = r1[0] + r1[1] + r1[2] + r1[3];
        g_c3[o] = b2[o] + Dmul * (r2[0] + r2[1] + r2[2] + r2[3]);
    }
}

// ---------- g_Wc: [o][k] bf16. 16 outputs rows per block ----------
__global__ __launch_bounds__(256) void pre_wc16(const float* __restrict__ W1,
                                                const float* __restrict__ W2) {
    __shared__ float w2s[16][FDIM];
    int tid = threadIdx.x;
    int ob = blockIdx.x * 16;
    #pragma unroll
    for (int i = 0; i < 16; ++i)
        w2s[i][tid] = W2[(size_t)(ob + i) * K2 + FDIM + tid];
    __syncthreads();
    float acc[16];
    #pragma unroll
    for (int i = 0; i < 16; ++i) acc[i] = 0.f;
    #pragma unroll 8
    for (int j = 0; j < FDIM; ++j) {
        float w1v = W1[(size_t)j * K2 + tid];          // C1[o,k]=sum_j W2b[o,j]*W1[j,k], k=tid
        #pragma unroll
        for (int i = 0; i < 16; ++i) acc[i] = fmaf(w2s[i][j], w1v, acc[i]);
    }
    #pragma unroll
    for (int i = 0; i < 16; ++i) {
        g_Wc[(size_t)(ob + i) * K2 + FDIM + tid] = f2bf(acc[i]);
        g_Wc[(size_t)(ob + i) * K2 + tid]        = f2bf(W2[(size_t)(ob + i) * K2 + tid]);
    }
}

// ---------- main: 32 rows/block. gather(bf16,swizzled LDS) + MFMA + normalize ----------
__global__ __launch_bounds__(256, 4) void gs_main(
    const float* __restrict__ feat_data,
    const float* __restrict__ feats,
    const int*   __restrict__ adj,
    const int*   __restrict__ in1, int B1,
    const int*   __restrict__ in2, int B2,
    const int*   __restrict__ neg, int Bn,
    float* __restrict__ out)
{
    __shared__ __align__(16) char lds[TM * 1024];   // Xs bf16 [32][512]; reused as f32 [32][256]
    __shared__ float Sdeg[TM];

    int tid  = threadIdx.x;
    int wave = tid >> 6, lane = tid & 63;
    int base = blockIdx.x * TM;
    int total = B1 + B2 + Bn;
    const float4* fd4 = (const float4*)feat_data;

    // ---- phase 1: gather. wave handles node m = g*4+wave
    for (int g = 0; g < 8; ++g) {
        int m = g * 4 + wave;
        int t = base + m;
        int swz = (m & 7) << 4;
        char* rowp = lds + m * 1024;
        int boff = (lane * 8) ^ swz;
        if (t >= total) {
            ushort4 z = make_ushort4(0, 0, 0, 0);
            *(ushort4*)(rowp + boff) = z;
            *(ushort4*)(rowp + 512 + boff) = z;
            if (lane == 0) Sdeg[m] = 0.f;
            continue;
        }
        int node = (t < B1) ? in1[t] : ((t < B1 + B2) ? in2[t - B1] : neg[t - B1 - B2]);

        int idx = 0; float deg = 0.f;
        if (lane < DNB) {
            idx = adj[(size_t)node * DNB + lane];
            deg = feats[(size_t)idx * FDIM];
        }
        float4 nf = fd4[(size_t)node * 64 + lane];

        float4 s0 = make_float4(0.f,0.f,0.f,0.f), s1 = s0, s2 = s0, s3 = s0;
        #pragma unroll
        for (int d = 0; d < DNB; d += 4) {
            int n0 = __shfl(idx, d);
            int n1 = __shfl(idx, d + 1);
            int n2 = __shfl(idx, d + 2);
            int n3 = __shfl(idx, d + 3);
            float4 v0 = fd4[(size_t)n0 * 64 + lane];
            float4 v1 = fd4[(size_t)n1 * 64 + lane];
            float4 v2 = fd4[(size_t)n2 * 64 + lane];
            float4 v3 = fd4[(size_t)n3 * 64 + lane];
            s0.x += v0.x; s0.y += v0.y; s0.z += v0.z; s0.w += v0.w;
            s1.x += v1.x; s1.y += v1.y; s1.z += v1.z; s1.w += v1.w;
            s2.x += v2.x; s2.y += v2.y; s2.z += v2.z; s2.w += v2.w;
            s3.x += v3.x; s3.y += v3.y; s3.z += v3.z; s3.w += v3.w;
        }
        #pragma unroll
        for (int d2 = 16; d2; d2 >>= 1) deg += __shfl_down(deg, d2);
        if (lane == 0) Sdeg[m] = deg;

        float ax = (s0.x + s1.x) + (s2.x + s3.x);
        float ay = (s0.y + s1.y) + (s2.y + s3.y);
        float az = (s0.z + s1.z) + (s2.z + s3.z);
        float aw = (s0.w + s1.w) + (s2.w + s3.w);

        ushort4 nfh = make_ushort4(f2bf(nf.x), f2bf(nf.y), f2bf(nf.z), f2bf(nf.w));
        ushort4 ah  = make_ushort4(f2bf(ax), f2bf(ay), f2bf(az), f2bf(aw));
        *(ushort4*)(rowp + boff) = nfh;          // k = 4*lane .. +3   (NF half)
        *(ushort4*)(rowp + 512 + boff) = ah;     // k = 256+4*lane ..  (A half)
    }
    __syncthreads();

    // ---- phase 2: MFMA. wave w: cols n0=w*64 (4 tiles), rows 0..31 (2 tiles)
    int l15 = lane & 15, lg = lane >> 4;
    int swzA = (l15 & 7) << 4;                   // rows m and m+16 share (m&7)
    f32x4 acc[2][4];
    #pragma unroll
    for (int mt = 0; mt < 2; ++mt)
        #pragma unroll
        for (int nt = 0; nt < 4; ++nt) acc[mt][nt] = (f32x4){0.f, 0.f, 0.f, 0.f};

    const char* pA0 = lds + (size_t)l15 * 1024;
    const char* pA1 = lds + (size_t)(16 + l15) * 1024;
    const unsigned short* wcB = g_Wc + (size_t)(wave * 64 + l15) * K2 + lg * 8;

    #pragma unroll 4
    for (int kk = 0; kk < K2; kk += 32) {
        int kb = kk * 2 + lg * 16;
        bf16x8 a0 = *(const bf16x8*)(pA0 + (kb ^ swzA));
        bf16x8 a1 = *(const bf16x8*)(pA1 + (kb ^ swzA));
        #pragma unroll
        for (int nt = 0; nt < 4; ++nt) {
            bf16x8 b = *(const bf16x8*)(wcB + (size_t)nt * 16 * K2 + kk);
            acc[0][nt] = __builtin_amdgcn_mfma_f32_16x16x32_bf16(a0, b, acc[0][nt], 0, 0, 0);
            acc[1][nt] = __builtin_amdgcn_mfma_f32_16x16x32_bf16(a1, b, acc[1][nt], 0, 0, 0);
        }
    }
    __syncthreads();                             // all waves done reading Xs

    // ---- stage raw acc to LDS as f32 [32][256]
    float* outf = (float*)lds;
    #pragma unroll
    for (int mt = 0; mt < 2; ++mt)
        #pragma unroll
        for (int nt = 0; nt < 4; ++nt)
            #pragma unroll
            for (int r = 0; r < 4; ++r) {
                int row = mt * 16 + lg * 4 + r;  // HW-verified D layout
                int col = wave * 64 + nt * 16 + l15;
                outf[row * 256 + col] = acc[mt][nt][r];
            }
    __syncthreads();

    // ---- epilogue: v = acc + Sdeg*c2 + c3 (fp32), L2-normalize, store
    float4 c2v = *(const float4*)(g_c2 + lane * 4);
    float4 c3v = *(const float4*)(g_c3 + lane * 4);
    for (int r = 0; r < 8; ++r) {
        int row = wave * 8 + r;
        int t = base + row;
        if (t >= total) break;                   // wave-uniform
        float sd = Sdeg[row];
        float4 v = *(float4*)(outf + row * 256 + lane * 4);
        v.x += sd * c2v.x + c3v.x;
        v.y += sd * c2v.y + c3v.y;
        v.z += sd * c2v.z + c3v.z;
        v.w += sd * c2v.w + c3v.w;
        float ss = v.x * v.x + v.y * v.y + v.z * v.z + v.w * v.w;
        #pragma unroll
        for (int s = 32; s; s >>= 1) ss += __shfl_xor(ss, s);
        float inv = 1.0f / fmaxf(sqrtf(ss), 1e-12f);
        v.x *= inv; v.y *= inv; v.z *= inv; v.w *= inv;
        *(float4*)(out + (size_t)t * FDIM + lane * 4) = v;
    }
}

extern "C" void kernel_launch(void* const* d_in, const int* in_sizes, int n_in,
                              void* d_out, int out_size, void* d_ws, size_t ws_size,
                              hipStream_t stream) {
    const float* feat_data = (const float*)d_in[0];
    const float* feats     = (const float*)d_in[1];
    const float* W1        = (const float*)d_in[2];
    const float* b1        = (const float*)d_in[3];
    const float* W2        = (const float*)d_in[4];
    const float* b2        = (const float*)d_in[5];
    const int*   adj       = (const int*)d_in[6];
    const int*   in1       = (const int*)d_in[7];
    const int*   in2       = (const int*)d_in[8];
    const int*   neg       = (const int*)d_in[9];

    int B1 = in_sizes[7];
    int B2 = in_sizes[8];
    int Bn = in_sizes[9];
    int N  = in_sizes[0] / FDIM;
    int D  = in_sizes[6] / N;   // == 32

    float* out = (float*)d_out;

    pre_w1s<<<FDIM, 64, 0, stream>>>(W1);
    pre_wc16<<<FDIM / 16, 256, 0, stream>>>(W1, W2);
    pre_c23<<<FDIM, 256, 0, stream>>>(W2, b1, b2, (float)D);

    int total = B1 + B2 + Bn;
    int nblocks = (total + TM - 1) / TM;
    gs_main<<<nblocks, 256, 0, stream>>>(feat_data, feats, adj,
                                         in1, B1, in2, B2, neg, Bn, out);
}

// Round 3
// 128.456 us; speedup vs baseline: 1.5877x; 1.5877x over previous
//
#include <hip/hip_runtime.h>
#include <hip/hip_bf16.h>

#define FDIM 256
#define K2   512
#define DNB  32
#define TM   32
#define NMAX 100000
#define TMAX 20480

typedef __attribute__((ext_vector_type(8))) short bf16x8;
typedef __attribute__((ext_vector_type(4))) float f32x4;

// Device-global scratch & precomputed weights (fully rewritten every launch).
__device__ __align__(16) unsigned short g_FD[(size_t)NMAX * FDIM]; // bf16 feat_data
__device__ float g_deg[NMAX];                                      // feats[n][0]
__device__ __align__(16) unsigned short g_X[(size_t)TMAX * K2];    // bf16 gathered rows
__device__ float g_Sdeg[TMAX];
__device__ __align__(16) unsigned short g_Wc[FDIM * K2];           // [o][k] bf16
__device__ float g_c2[FDIM];
__device__ float g_c3[FDIM];

__device__ __forceinline__ unsigned short f2bf(float f) {
    __hip_bfloat16 h = __float2bfloat16(f);
    return *reinterpret_cast<unsigned short*>(&h);
}
__device__ __forceinline__ float bf2f(unsigned short u) {
    return __uint_as_float(((unsigned)u) << 16);
}

// ---------- 1) feat_data -> bf16 table + degree table ----------
__global__ __launch_bounds__(256) void conv_fd(const float* __restrict__ fd,
                                               const float* __restrict__ feats, int N) {
    int wave = threadIdx.x >> 6, lane = threadIdx.x & 63;
    int n = blockIdx.x * 4 + wave;
    if (n >= N) return;
    float4 v = ((const float4*)fd)[(size_t)n * 64 + lane];
    ushort4 h = make_ushort4(f2bf(v.x), f2bf(v.y), f2bf(v.z), f2bf(v.w));
    *(ushort4*)(g_FD + (size_t)n * FDIM + lane * 4) = h;
    if (lane == 0) g_deg[n] = feats[(size_t)n * FDIM];
}

// ---------- 2) combined weights: g_Wc, c2, c3 in ONE kernel ----------
// block o, threads k' in [0,512): Ccomb[o,k'] = sum_j W2[o,256+j] * W1[j,k']
// k'<256 -> C1 half of g_Wc; sum over k'>=256 -> c2[o].
__global__ __launch_bounds__(512) void pre_all(const float* __restrict__ W1,
                                               const float* __restrict__ W2,
                                               const float* __restrict__ b1,
                                               const float* __restrict__ b2,
                                               float Dmul) {
    int o = blockIdx.x, k = threadIdx.x;
    __shared__ float w2s[FDIM];
    __shared__ float rv[8], ru[8];
    if (k < FDIM) w2s[k] = W2[(size_t)o * K2 + FDIM + k];
    __syncthreads();

    float acc = 0.f;
    #pragma unroll 8
    for (int j = 0; j < FDIM; ++j)
        acc = fmaf(w2s[j], W1[(size_t)j * K2 + k], acc);

    if (k < FDIM) {
        g_Wc[(size_t)o * K2 + FDIM + k] = f2bf(acc);            // C1 half
        g_Wc[(size_t)o * K2 + k]        = f2bf(W2[(size_t)o * K2 + k]); // W2a half
    }
    float v = (k >= FDIM) ? acc : 0.f;          // -> c2
    float u = (k < FDIM) ? b1[k] * w2s[k] : 0.f; // -> c3 dot
    #pragma unroll
    for (int s = 32; s; s >>= 1) { v += __shfl_down(v, s); u += __shfl_down(u, s); }
    if ((k & 63) == 0) { rv[k >> 6] = v; ru[k >> 6] = u; }
    __syncthreads();
    if (k == 0) {
        float sv = 0.f, su = 0.f;
        #pragma unroll
        for (int w = 0; w < 8; ++w) { sv += rv[w]; su += ru[w]; }
        g_c2[o] = sv;
        g_c3[o] = b2[o] + Dmul * su;
    }
}

// ---------- 3) gather: one wave per node, no LDS, deep MLP ----------
__global__ __launch_bounds__(256, 6) void gather(
    const int* __restrict__ adj,
    const int* __restrict__ in1, int B1,
    const int* __restrict__ in2, int B2,
    const int* __restrict__ neg, int total)
{
    int wave = threadIdx.x >> 6, lane = threadIdx.x & 63;
    int t = blockIdx.x * 4 + wave;
    if (t >= total) return;
    int node = (t < B1) ? in1[t] : ((t < B1 + B2) ? in2[t - B1] : neg[t - B1 - B2]);

    int idx = 0; float deg = 0.f;
    if (lane < DNB) {
        idx = adj[(size_t)node * DNB + lane];
        deg = g_deg[idx];
    }
    #pragma unroll
    for (int s = 16; s; s >>= 1) deg += __shfl_down(deg, s);
    if (lane == 0) g_Sdeg[t] = deg;

    // node row passthrough (already bf16)
    ushort4 nf = *(const ushort4*)(g_FD + (size_t)node * FDIM + lane * 4);
    *(ushort4*)(g_X + (size_t)t * K2 + lane * 4) = nf;

    // neighbor sum: 8 loads in flight per step
    f32x4 acc = {0.f, 0.f, 0.f, 0.f};
    #pragma unroll
    for (int d = 0; d < DNB; d += 8) {
        ushort4 v[8];
        #pragma unroll
        for (int u = 0; u < 8; ++u) {
            int nb = __shfl(idx, d + u);
            v[u] = *(const ushort4*)(g_FD + (size_t)nb * FDIM + lane * 4);
        }
        #pragma unroll
        for (int u = 0; u < 8; ++u) {
            acc.x += bf2f(v[u].x);
            acc.y += bf2f(v[u].y);
            acc.z += bf2f(v[u].z);
            acc.w += bf2f(v[u].w);
        }
    }
    ushort4 ah = make_ushort4(f2bf(acc.x), f2bf(acc.y), f2bf(acc.z), f2bf(acc.w));
    *(ushort4*)(g_X + (size_t)t * K2 + FDIM + lane * 4) = ah;
}

// ---------- 4) GEMM (MFMA) + degree term + L2 normalize ----------
__global__ __launch_bounds__(256, 4) void gemm_norm(float* __restrict__ out, int total)
{
    __shared__ __align__(16) char lds[TM * 1024];  // bf16 [32][512]; reused f32 [32][256]
    __shared__ float Sdeg[TM];

    int tid = threadIdx.x, wave = tid >> 6, lane = tid & 63;
    int base = blockIdx.x * TM;

    if (tid < TM) {
        int t = base + tid;
        Sdeg[tid] = (t < total) ? g_Sdeg[t] : 0.f;
    }
    // stage X rows (coalesced 16B/lane), swizzled LDS writes
    #pragma unroll
    for (int i = 0; i < 8; ++i) {
        int row = wave * 8 + i;
        int t = base + row;
        bf16x8 v = {0, 0, 0, 0, 0, 0, 0, 0};
        if (t < total) v = *(const bf16x8*)(g_X + (size_t)t * K2 + lane * 8);
        *(bf16x8*)(lds + row * 1024 + ((lane * 16) ^ ((row & 7) << 4))) = v;
    }
    __syncthreads();

    // MFMA: wave w -> cols w*64 (4 tiles of 16), rows 0..31 (2 tiles)
    int l15 = lane & 15, lg = lane >> 4;
    int swzA = (l15 & 7) << 4;
    f32x4 acc[2][4];
    #pragma unroll
    for (int mt = 0; mt < 2; ++mt)
        #pragma unroll
        for (int nt = 0; nt < 4; ++nt) acc[mt][nt] = (f32x4){0.f, 0.f, 0.f, 0.f};

    const char* pA0 = lds + (size_t)l15 * 1024;
    const char* pA1 = lds + (size_t)(16 + l15) * 1024;
    const unsigned short* wcB = g_Wc + (size_t)(wave * 64 + l15) * K2 + lg * 8;

    #pragma unroll 4
    for (int kk = 0; kk < K2; kk += 32) {
        int kb = kk * 2 + lg * 16;
        bf16x8 a0 = *(const bf16x8*)(pA0 + (kb ^ swzA));
        bf16x8 a1 = *(const bf16x8*)(pA1 + (kb ^ swzA));
        #pragma unroll
        for (int nt = 0; nt < 4; ++nt) {
            bf16x8 b = *(const bf16x8*)(wcB + (size_t)nt * 16 * K2 + kk);
            acc[0][nt] = __builtin_amdgcn_mfma_f32_16x16x32_bf16(a0, b, acc[0][nt], 0, 0, 0);
            acc[1][nt] = __builtin_amdgcn_mfma_f32_16x16x32_bf16(a1, b, acc[1][nt], 0, 0, 0);
        }
    }
    __syncthreads();

    // stage raw acc to LDS as f32 [32][256] (HW-verified D layout)
    float* outf = (float*)lds;
    #pragma unroll
    for (int mt = 0; mt < 2; ++mt)
        #pragma unroll
        for (int nt = 0; nt < 4; ++nt)
            #pragma unroll
            for (int r = 0; r < 4; ++r) {
                int row = mt * 16 + lg * 4 + r;
                int col = wave * 64 + nt * 16 + l15;
                outf[row * 256 + col] = acc[mt][nt][r];
            }
    __syncthreads();

    // epilogue: v = acc + Sdeg*c2 + c3 (fp32), L2-normalize, store
    float4 c2v = *(const float4*)(g_c2 + lane * 4);
    float4 c3v = *(const float4*)(g_c3 + lane * 4);
    for (int r = 0; r < 8; ++r) {
        int row = wave * 8 + r;
        int t = base + row;
        if (t >= total) break;                   // wave-uniform
        float sd = Sdeg[row];
        float4 v = *(float4*)(outf + row * 256 + lane * 4);
        v.x += sd * c2v.x + c3v.x;
        v.y += sd * c2v.y + c3v.y;
        v.z += sd * c2v.z + c3v.z;
        v.w += sd * c2v.w + c3v.w;
        float ss = v.x * v.x + v.y * v.y + v.z * v.z + v.w * v.w;
        #pragma unroll
        for (int s = 32; s; s >>= 1) ss += __shfl_xor(ss, s);
        float inv = 1.0f / fmaxf(sqrtf(ss), 1e-12f);
        v.x *= inv; v.y *= inv; v.z *= inv; v.w *= inv;
        *(float4*)(out + (size_t)t * FDIM + lane * 4) = v;
    }
}

extern "C" void kernel_launch(void* const* d_in, const int* in_sizes, int n_in,
                              void* d_out, int out_size, void* d_ws, size_t ws_size,
                              hipStream_t stream) {
    const float* feat_data = (const float*)d_in[0];
    const float* feats     = (const float*)d_in[1];
    const float* W1        = (const float*)d_in[2];
    const float* b1        = (const float*)d_in[3];
    const float* W2        = (const float*)d_in[4];
    const float* b2        = (const float*)d_in[5];
    const int*   adj       = (const int*)d_in[6];
    const int*   in1       = (const int*)d_in[7];
    const int*   in2       = (const int*)d_in[8];
    const int*   neg       = (const int*)d_in[9];

    int B1 = in_sizes[7];
    int B2 = in_sizes[8];
    int Bn = in_sizes[9];
    int N  = in_sizes[0] / FDIM;
    int D  = in_sizes[6] / N;   // == 32

    float* out = (float*)d_out;
    int total = B1 + B2 + Bn;

    conv_fd<<<(N + 3) / 4, 256, 0, stream>>>(feat_data, feats, N);
    pre_all<<<FDIM, 512, 0, stream>>>(W1, W2, b1, b2, (float)D);
    gather<<<(total + 3) / 4, 256, 0, stream>>>(adj, in1, B1, in2, B2, neg, total);
    gemm_norm<<<(total + TM - 1) / TM, 256, 0, stream>>>(out, total);
}

// Round 4
// 115.736 us; speedup vs baseline: 1.7622x; 1.1099x over previous
//
#include <hip/hip_runtime.h>
#include <hip/hip_bf16.h>

#define FDIM 256
#define K2   512
#define DNB  32
#define TM   32
#define NMAX 100000
#define TMAX 20480

typedef __attribute__((ext_vector_type(8))) short bf16x8;
typedef __attribute__((ext_vector_type(4))) float f32x4;

// Device-global scratch & precomputed weights (fully rewritten every launch).
__device__ __align__(16) unsigned short g_FD[(size_t)NMAX * FDIM]; // bf16 feat_data
__device__ float g_deg[NMAX];                                      // feats[n][0]
__device__ __align__(16) unsigned short g_X[(size_t)TMAX * K2];    // bf16 gathered rows
__device__ float g_Sdeg[TMAX];
__device__ __align__(16) unsigned short g_Wc[FDIM * K2];           // [o][k] bf16
__device__ float g_c2[FDIM];
__device__ float g_c3[FDIM];

__device__ __forceinline__ unsigned short f2bf(float f) {
    __hip_bfloat16 h = __float2bfloat16(f);
    return *reinterpret_cast<unsigned short*>(&h);
}
__device__ __forceinline__ float bf2f(unsigned short u) {
    return __uint_as_float(((unsigned)u) << 16);
}

// ---------- 1) prep: blocks [0,256) combine weights; blocks [256,...) convert feat_data
__global__ __launch_bounds__(512) void prep(const float* __restrict__ fd,
                                            const float* __restrict__ feats,
                                            const float* __restrict__ W1,
                                            const float* __restrict__ W2,
                                            const float* __restrict__ b1,
                                            const float* __restrict__ b2,
                                            float Dmul, int N) {
    __shared__ float w2s[FDIM];
    __shared__ float rv[8], ru[8];
    int bid = blockIdx.x;
    int tid = threadIdx.x;

    if (bid >= 256) {
        // feat_data -> bf16 table + degree table (8 rows/block, 1 row/wave)
        int wave = tid >> 6, lane = tid & 63;
        int n = (bid - 256) * 8 + wave;
        if (n >= N) return;
        float4 v = ((const float4*)fd)[(size_t)n * 64 + lane];
        ushort4 h = make_ushort4(f2bf(v.x), f2bf(v.y), f2bf(v.z), f2bf(v.w));
        *(ushort4*)(g_FD + (size_t)n * FDIM + lane * 4) = h;
        if (lane == 0) g_deg[n] = feats[(size_t)n * FDIM];
        return;
    }

    // ---- weight combine: o = bid, k' = tid in [0,512)
    int o = bid, k = tid;
    if (k < FDIM) w2s[k] = W2[(size_t)o * K2 + FDIM + k];
    __syncthreads();

    float acc = 0.f;
    #pragma unroll 8
    for (int j = 0; j < FDIM; ++j)
        acc = fmaf(w2s[j], W1[(size_t)j * K2 + k], acc);

    if (k < FDIM) {
        g_Wc[(size_t)o * K2 + FDIM + k] = f2bf(acc);                    // C1 half
        g_Wc[(size_t)o * K2 + k]        = f2bf(W2[(size_t)o * K2 + k]); // W2a half
    }
    float v = (k >= FDIM) ? acc : 0.f;            // -> c2
    float u = (k < FDIM) ? b1[k] * w2s[k] : 0.f;  // -> c3 dot
    #pragma unroll
    for (int s = 32; s; s >>= 1) { v += __shfl_down(v, s); u += __shfl_down(u, s); }
    if ((k & 63) == 0) { rv[k >> 6] = v; ru[k >> 6] = u; }
    __syncthreads();
    if (k == 0) {
        float sv = 0.f, su = 0.f;
        #pragma unroll
        for (int w = 0; w < 8; ++w) { sv += rv[w]; su += ru[w]; }
        g_c2[o] = sv;
        g_c3[o] = b2[o] + Dmul * su;
    }
}

// ---------- 2) gather: one wave per node; 2 neighbors in parallel (16B/lane) ----------
__global__ __launch_bounds__(256, 6) void gather(
    const int* __restrict__ adj,
    const int* __restrict__ in1, int B1,
    const int* __restrict__ in2, int B2,
    const int* __restrict__ neg, int total)
{
    int wave = threadIdx.x >> 6, lane = threadIdx.x & 63;
    int half = lane >> 5, l31 = lane & 31;
    int t = blockIdx.x * 4 + wave;
    if (t >= total) return;
    int node = (t < B1) ? in1[t] : ((t < B1 + B2) ? in2[t - B1] : neg[t - B1 - B2]);

    int idx = 0; float deg = 0.f;
    if (lane < DNB) {
        idx = adj[(size_t)node * DNB + lane];
        deg = g_deg[idx];
    }
    #pragma unroll
    for (int s = 16; s; s >>= 1) deg += __shfl_down(deg, s);
    if (lane == 0) g_Sdeg[t] = deg;

    // node row passthrough (already bf16): 8B/lane
    ushort4 nf = *(const ushort4*)(g_FD + (size_t)node * FDIM + lane * 4);
    *(ushort4*)(g_X + (size_t)t * K2 + lane * 4) = nf;

    // neighbor sum: half-wave h covers neighbors d+2u+h; lane covers cols l31*8..+7
    float acc[8];
    #pragma unroll
    for (int k = 0; k < 8; ++k) acc[k] = 0.f;
    #pragma unroll
    for (int d = 0; d < DNB; d += 8) {
        bf16x8 v[4];
        #pragma unroll
        for (int u = 0; u < 4; ++u) {
            int nb = __shfl(idx, d + u * 2 + half);
            v[u] = *(const bf16x8*)(g_FD + (size_t)nb * FDIM + l31 * 8);
        }
        #pragma unroll
        for (int u = 0; u < 4; ++u)
            #pragma unroll
            for (int k = 0; k < 8; ++k)
                acc[k] += bf2f((unsigned short)v[u][k]);
    }
    // combine even/odd-neighbor halves
    #pragma unroll
    for (int k = 0; k < 8; ++k) acc[k] += __shfl_xor(acc[k], 32);

    if (lane < 32) {
        bf16x8 ah;
        #pragma unroll
        for (int k = 0; k < 8; ++k) ah[k] = (short)f2bf(acc[k]);
        *(bf16x8*)(g_X + (size_t)t * K2 + FDIM + l31 * 8) = ah;
    }
}

// ---------- 3) GEMM (MFMA) + degree term + L2 normalize ----------
__global__ __launch_bounds__(256, 4) void gemm_norm(float* __restrict__ out, int total)
{
    __shared__ __align__(16) char lds[TM * 1024];  // bf16 [32][512]; reused f32 [32][256]
    __shared__ float Sdeg[TM];

    int tid = threadIdx.x, wave = tid >> 6, lane = tid & 63;
    int base = blockIdx.x * TM;

    if (tid < TM) {
        int t = base + tid;
        Sdeg[tid] = (t < total) ? g_Sdeg[t] : 0.f;
    }
    // stage X rows (coalesced 16B/lane), swizzled LDS writes
    #pragma unroll
    for (int i = 0; i < 8; ++i) {
        int row = wave * 8 + i;
        int t = base + row;
        bf16x8 v = {0, 0, 0, 0, 0, 0, 0, 0};
        if (t < total) v = *(const bf16x8*)(g_X + (size_t)t * K2 + lane * 8);
        *(bf16x8*)(lds + row * 1024 + ((lane * 16) ^ ((row & 7) << 4))) = v;
    }
    __syncthreads();

    // MFMA: wave w -> cols w*64 (4 tiles of 16), rows 0..31 (2 tiles)
    int l15 = lane & 15, lg = lane >> 4;
    int swzA = (l15 & 7) << 4;
    f32x4 acc[2][4];
    #pragma unroll
    for (int mt = 0; mt < 2; ++mt)
        #pragma unroll
        for (int nt = 0; nt < 4; ++nt) acc[mt][nt] = (f32x4){0.f, 0.f, 0.f, 0.f};

    const char* pA0 = lds + (size_t)l15 * 1024;
    const char* pA1 = lds + (size_t)(16 + l15) * 1024;
    const unsigned short* wcB = g_Wc + (size_t)(wave * 64 + l15) * K2 + lg * 8;

    #pragma unroll 4
    for (int kk = 0; kk < K2; kk += 32) {
        int kb = kk * 2 + lg * 16;
        bf16x8 a0 = *(const bf16x8*)(pA0 + (kb ^ swzA));
        bf16x8 a1 = *(const bf16x8*)(pA1 + (kb ^ swzA));
        #pragma unroll
        for (int nt = 0; nt < 4; ++nt) {
            bf16x8 b = *(const bf16x8*)(wcB + (size_t)nt * 16 * K2 + kk);
            acc[0][nt] = __builtin_amdgcn_mfma_f32_16x16x32_bf16(a0, b, acc[0][nt], 0, 0, 0);
            acc[1][nt] = __builtin_amdgcn_mfma_f32_16x16x32_bf16(a1, b, acc[1][nt], 0, 0, 0);
        }
    }
    __syncthreads();

    // stage raw acc to LDS as f32 [32][256] (HW-verified D layout)
    float* outf = (float*)lds;
    #pragma unroll
    for (int mt = 0; mt < 2; ++mt)
        #pragma unroll
        for (int nt = 0; nt < 4; ++nt)
            #pragma unroll
            for (int r = 0; r < 4; ++r) {
                int row = mt * 16 + lg * 4 + r;
                int col = wave * 64 + nt * 16 + l15;
                outf[row * 256 + col] = acc[mt][nt][r];
            }
    __syncthreads();

    // epilogue: v = acc + Sdeg*c2 + c3 (fp32), L2-normalize, store
    float4 c2v = *(const float4*)(g_c2 + lane * 4);
    float4 c3v = *(const float4*)(g_c3 + lane * 4);
    for (int r = 0; r < 8; ++r) {
        int row = wave * 8 + r;
        int t = base + row;
        if (t >= total) break;                   // wave-uniform
        float sd = Sdeg[row];
        float4 v = *(float4*)(outf + row * 256 + lane * 4);
        v.x += sd * c2v.x + c3v.x;
        v.y += sd * c2v.y + c3v.y;
        v.z += sd * c2v.z + c3v.z;
        v.w += sd * c2v.w + c3v.w;
        float ss = v.x * v.x + v.y * v.y + v.z * v.z + v.w * v.w;
        #pragma unroll
        for (int s = 32; s; s >>= 1) ss += __shfl_xor(ss, s);
        float inv = 1.0f / fmaxf(sqrtf(ss), 1e-12f);
        v.x *= inv; v.y *= inv; v.z *= inv; v.w *= inv;
        *(float4*)(out + (size_t)t * FDIM + lane * 4) = v;
    }
}

extern "C" void kernel_launch(void* const* d_in, const int* in_sizes, int n_in,
                              void* d_out, int out_size, void* d_ws, size_t ws_size,
                              hipStream_t stream) {
    const float* feat_data = (const float*)d_in[0];
    const float* feats     = (const float*)d_in[1];
    const float* W1        = (const float*)d_in[2];
    const float* b1        = (const float*)d_in[3];
    const float* W2        = (const float*)d_in[4];
    const float* b2        = (const float*)d_in[5];
    const int*   adj       = (const int*)d_in[6];
    const int*   in1       = (const int*)d_in[7];
    const int*   in2       = (const int*)d_in[8];
    const int*   neg       = (const int*)d_in[9];

    int B1 = in_sizes[7];
    int B2 = in_sizes[8];
    int Bn = in_sizes[9];
    int N  = in_sizes[0] / FDIM;
    int D  = in_sizes[6] / N;   // == 32

    float* out = (float*)d_out;
    int total = B1 + B2 + Bn;

    int convBlocks = (N + 7) / 8;
    prep<<<256 + convBlocks, 512, 0, stream>>>(feat_data, feats, W1, W2, b1, b2,
                                               (float)D, N);
    gather<<<(total + 3) / 4, 256, 0, stream>>>(adj, in1, B1, in2, B2, neg, total);
    gemm_norm<<<(total + TM - 1) / TM, 256, 0, stream>>>(out, total);
}

// Round 5
// 113.255 us; speedup vs baseline: 1.8008x; 1.0219x over previous
//
#include <hip/hip_runtime.h>
#include <hip/hip_bf16.h>

#define FDIM 256
#define K2   512
#define DNB  32
#define TM   32
#define NMAX 100000
#define TMAX 20480

typedef __attribute__((ext_vector_type(8))) short bf16x8;
typedef __attribute__((ext_vector_type(4))) float f32x4;

// Device-global scratch & precomputed weights (fully rewritten every launch).
__device__ __align__(16) unsigned short g_FD[(size_t)NMAX * FDIM]; // bf16 feat_data
__device__ float g_deg[NMAX];                                      // feats[n][0]
__device__ __align__(16) unsigned short g_X[(size_t)TMAX * K2];    // bf16 gathered rows
__device__ float g_Sdeg[TMAX];
__device__ __align__(16) unsigned short g_Wc[FDIM * K2];           // [o][k] bf16
__device__ float g_c2[FDIM];
__device__ float g_c3[FDIM];

__device__ __forceinline__ unsigned short f2bf(float f) {
    __hip_bfloat16 h = __float2bfloat16(f);
    return *reinterpret_cast<unsigned short*>(&h);
}
__device__ __forceinline__ float bf2f(unsigned short u) {
    return __uint_as_float(((unsigned)u) << 16);
}

// ---------- 1) prep: blocks [0,256) combine weights; blocks [256,...) convert feat_data
// Conversion region: strided 8*float4 per thread -> 8 independent coalesced loads in flight.
__global__ __launch_bounds__(512) void prep(const float* __restrict__ fd,
                                            const float* __restrict__ feats,
                                            const float* __restrict__ W1,
                                            const float* __restrict__ W2,
                                            const float* __restrict__ b1,
                                            const float* __restrict__ b2,
                                            float Dmul, int N) {
    __shared__ float w2s[FDIM];
    __shared__ float rv[8], ru[8];
    int bid = blockIdx.x;
    int tid = threadIdx.x;

    if (bid >= 256) {
        int cb = bid - 256;
        size_t total4 = (size_t)N * (FDIM / 4);
        size_t base = (size_t)cb * 4096 + tid;
        const float4* in4 = (const float4*)fd;
        ushort4* out4 = (ushort4*)g_FD;

        float4 v[8];
        bool ok[8];
        #pragma unroll
        for (int j = 0; j < 8; ++j) {
            size_t i = base + (size_t)j * 512;
            ok[j] = (i < total4);
            if (ok[j]) v[j] = in4[i];
        }
        #pragma unroll
        for (int j = 0; j < 8; ++j) {
            if (ok[j]) {
                size_t i = base + (size_t)j * 512;
                out4[i] = make_ushort4(f2bf(v[j].x), f2bf(v[j].y),
                                       f2bf(v[j].z), f2bf(v[j].w));
            }
        }
        // degree table rides on the first blocks
        int n = cb * 512 + tid;
        if (n < N) g_deg[n] = feats[(size_t)n * FDIM];
        return;
    }

    // ---- weight combine: o = bid, k' = tid in [0,512)
    int o = bid, k = tid;
    if (k < FDIM) w2s[k] = W2[(size_t)o * K2 + FDIM + k];
    __syncthreads();

    float acc = 0.f;
    #pragma unroll 8
    for (int j = 0; j < FDIM; ++j)
        acc = fmaf(w2s[j], W1[(size_t)j * K2 + k], acc);

    if (k < FDIM) {
        g_Wc[(size_t)o * K2 + FDIM + k] = f2bf(acc);                    // C1 half
        g_Wc[(size_t)o * K2 + k]        = f2bf(W2[(size_t)o * K2 + k]); // W2a half
    }
    float v = (k >= FDIM) ? acc : 0.f;            // -> c2
    float u = (k < FDIM) ? b1[k] * w2s[k] : 0.f;  // -> c3 dot
    #pragma unroll
    for (int s = 32; s; s >>= 1) { v += __shfl_down(v, s); u += __shfl_down(u, s); }
    if ((k & 63) == 0) { rv[k >> 6] = v; ru[k >> 6] = u; }
    __syncthreads();
    if (k == 0) {
        float sv = 0.f, su = 0.f;
        #pragma unroll
        for (int w = 0; w < 8; ++w) { sv += rv[w]; su += ru[w]; }
        g_c2[o] = sv;
        g_c3[o] = b2[o] + Dmul * su;
    }
}

// ---------- 2) gather: one wave per node; 2 neighbors in parallel (16B/lane) ----------
__global__ __launch_bounds__(256, 6) void gather(
    const int* __restrict__ adj,
    const int* __restrict__ in1, int B1,
    const int* __restrict__ in2, int B2,
    const int* __restrict__ neg, int total)
{
    int wave = threadIdx.x >> 6, lane = threadIdx.x & 63;
    int half = lane >> 5, l31 = lane & 31;
    int t = blockIdx.x * 4 + wave;
    if (t >= total) return;
    int node = (t < B1) ? in1[t] : ((t < B1 + B2) ? in2[t - B1] : neg[t - B1 - B2]);

    int idx = 0; float deg = 0.f;
    if (lane < DNB) {
        idx = adj[(size_t)node * DNB + lane];
        deg = g_deg[idx];
    }
    #pragma unroll
    for (int s = 16; s; s >>= 1) deg += __shfl_down(deg, s);
    if (lane == 0) g_Sdeg[t] = deg;

    // node row passthrough (already bf16): 8B/lane
    ushort4 nf = *(const ushort4*)(g_FD + (size_t)node * FDIM + lane * 4);
    *(ushort4*)(g_X + (size_t)t * K2 + lane * 4) = nf;

    // neighbor sum: half-wave h covers neighbors d+2u+h; lane covers cols l31*8..+7
    float acc[8];
    #pragma unroll
    for (int k = 0; k < 8; ++k) acc[k] = 0.f;
    #pragma unroll
    for (int d = 0; d < DNB; d += 8) {
        bf16x8 v[4];
        #pragma unroll
        for (int u = 0; u < 4; ++u) {
            int nb = __shfl(idx, d + u * 2 + half);
            v[u] = *(const bf16x8*)(g_FD + (size_t)nb * FDIM + l31 * 8);
        }
        #pragma unroll
        for (int u = 0; u < 4; ++u)
            #pragma unroll
            for (int k = 0; k < 8; ++k)
                acc[k] += bf2f((unsigned short)v[u][k]);
    }
    // combine even/odd-neighbor halves
    #pragma unroll
    for (int k = 0; k < 8; ++k) acc[k] += __shfl_xor(acc[k], 32);

    if (lane < 32) {
        bf16x8 ah;
        #pragma unroll
        for (int k = 0; k < 8; ++k) ah[k] = (short)f2bf(acc[k]);
        *(bf16x8*)(g_X + (size_t)t * K2 + FDIM + l31 * 8) = ah;
    }
}

// ---------- 3) GEMM (MFMA) + degree term + L2 normalize ----------
__global__ __launch_bounds__(256, 4) void gemm_norm(float* __restrict__ out, int total)
{
    __shared__ __align__(16) char lds[TM * 1024];  // bf16 [32][512]; reused f32 [32][256]
    __shared__ float Sdeg[TM];

    int tid = threadIdx.x, wave = tid >> 6, lane = tid & 63;
    int base = blockIdx.x * TM;

    if (tid < TM) {
        int t = base + tid;
        Sdeg[tid] = (t < total) ? g_Sdeg[t] : 0.f;
    }
    // stage X rows (coalesced 16B/lane), swizzled LDS writes
    #pragma unroll
    for (int i = 0; i < 8; ++i) {
        int row = wave * 8 + i;
        int t = base + row;
        bf16x8 v = {0, 0, 0, 0, 0, 0, 0, 0};
        if (t < total) v = *(const bf16x8*)(g_X + (size_t)t * K2 + lane * 8);
        *(bf16x8*)(lds + row * 1024 + ((lane * 16) ^ ((row & 7) << 4))) = v;
    }
    __syncthreads();

    // MFMA: wave w -> cols w*64 (4 tiles of 16), rows 0..31 (2 tiles)
    int l15 = lane & 15, lg = lane >> 4;
    int swzA = (l15 & 7) << 4;
    f32x4 acc[2][4];
    #pragma unroll
    for (int mt = 0; mt < 2; ++mt)
        #pragma unroll
        for (int nt = 0; nt < 4; ++nt) acc[mt][nt] = (f32x4){0.f, 0.f, 0.f, 0.f};

    const char* pA0 = lds + (size_t)l15 * 1024;
    const char* pA1 = lds + (size_t)(16 + l15) * 1024;
    const unsigned short* wcB = g_Wc + (size_t)(wave * 64 + l15) * K2 + lg * 8;

    #pragma unroll 4
    for (int kk = 0; kk < K2; kk += 32) {
        int kb = kk * 2 + lg * 16;
        bf16x8 a0 = *(const bf16x8*)(pA0 + (kb ^ swzA));
        bf16x8 a1 = *(const bf16x8*)(pA1 + (kb ^ swzA));
        #pragma unroll
        for (int nt = 0; nt < 4; ++nt) {
            bf16x8 b = *(const bf16x8*)(wcB + (size_t)nt * 16 * K2 + kk);
            acc[0][nt] = __builtin_amdgcn_mfma_f32_16x16x32_bf16(a0, b, acc[0][nt], 0, 0, 0);
            acc[1][nt] = __builtin_amdgcn_mfma_f32_16x16x32_bf16(a1, b, acc[1][nt], 0, 0, 0);
        }
    }
    __syncthreads();

    // stage raw acc to LDS as f32 [32][256] (HW-verified D layout)
    float* outf = (float*)lds;
    #pragma unroll
    for (int mt = 0; mt < 2; ++mt)
        #pragma unroll
        for (int nt = 0; nt < 4; ++nt)
            #pragma unroll
            for (int r = 0; r < 4; ++r) {
                int row = mt * 16 + lg * 4 + r;
                int col = wave * 64 + nt * 16 + l15;
                outf[row * 256 + col] = acc[mt][nt][r];
            }
    __syncthreads();

    // epilogue: v = acc + Sdeg*c2 + c3 (fp32), L2-normalize, store
    float4 c2v = *(const float4*)(g_c2 + lane * 4);
    float4 c3v = *(const float4*)(g_c3 + lane * 4);
    for (int r = 0; r < 8; ++r) {
        int row = wave * 8 + r;
        int t = base + row;
        if (t >= total) break;                   // wave-uniform
        float sd = Sdeg[row];
        float4 v = *(float4*)(outf + row * 256 + lane * 4);
        v.x += sd * c2v.x + c3v.x;
        v.y += sd * c2v.y + c3v.y;
        v.z += sd * c2v.z + c3v.z;
        v.w += sd * c2v.w + c3v.w;
        float ss = v.x * v.x + v.y * v.y + v.z * v.z + v.w * v.w;
        #pragma unroll
        for (int s = 32; s; s >>= 1) ss += __shfl_xor(ss, s);
        float inv = 1.0f / fmaxf(sqrtf(ss), 1e-12f);
        v.x *= inv; v.y *= inv; v.z *= inv; v.w *= inv;
        *(float4*)(out + (size_t)t * FDIM + lane * 4) = v;
    }
}

extern "C" void kernel_launch(void* const* d_in, const int* in_sizes, int n_in,
                              void* d_out, int out_size, void* d_ws, size_t ws_size,
                              hipStream_t stream) {
    const float* feat_data = (const float*)d_in[0];
    const float* feats     = (const float*)d_in[1];
    const float* W1        = (const float*)d_in[2];
    const float* b1        = (const float*)d_in[3];
    const float* W2        = (const float*)d_in[4];
    const float* b2        = (const float*)d_in[5];
    const int*   adj       = (const int*)d_in[6];
    const int*   in1       = (const int*)d_in[7];
    const int*   in2       = (const int*)d_in[8];
    const int*   neg       = (const int*)d_in[9];

    int B1 = in_sizes[7];
    int B2 = in_sizes[8];
    int Bn = in_sizes[9];
    int N  = in_sizes[0] / FDIM;
    int D  = in_sizes[6] / N;   // == 32

    float* out = (float*)d_out;
    int total = B1 + B2 + Bn;

    size_t total4 = (size_t)N * (FDIM / 4);
    int convBlocks = (int)((total4 + 4095) / 4096);
    prep<<<256 + convBlocks, 512, 0, stream>>>(feat_data, feats, W1, W2, b1, b2,
                                               (float)D, N);
    gather<<<(total + 3) / 4, 256, 0, stream>>>(adj, in1, B1, in2, B2, neg, total);
    gemm_norm<<<(total + TM - 1) / TM, 256, 0, stream>>>(out, total);
}